// Round 2
// baseline (224.790 us; speedup 1.0000x reference)
//
#include <hip/hip_runtime.h>

#define SCAN_THREADS 256
#define EPT 8
#define CHUNK (SCAN_THREADS * EPT)   // 2048 elements per scan tile

typedef int   v4i __attribute__((ext_vector_type(4)));
typedef float v4f __attribute__((ext_vector_type(4)));

__device__ inline unsigned long long pack_sf(float v, unsigned flag) {
    return ((unsigned long long)flag << 32) | (unsigned long long)__float_as_uint(v);
}

// ---------------------------------------------------------------------------
// K1: filtered = residues * sigmoid(attrs @ w + b); scatter +/- into delta.
// tpre u tpost is a permutation of [0,2N) -> each slot written exactly once.
// 4 nodes per thread for scatter ILP.
__global__ void k1_filter_scatter(const float* __restrict__ attrs,
                                  const float* __restrict__ weight,
                                  const float* __restrict__ bias,
                                  const float* __restrict__ residues,
                                  const int* __restrict__ tpre,
                                  const int* __restrict__ tpost,
                                  float* __restrict__ delta,
                                  int N) {
    int u0 = (blockIdx.x * blockDim.x + threadIdx.x) * 4;
    v4f w0 = *(const v4f*)weight;
    v4f w1 = *(const v4f*)(weight + 4);
    float b = bias[0];
    if (u0 + 4 <= N) {
        v4f r  = __builtin_nontemporal_load((const v4f*)(residues + u0));
        v4i pre  = *(const v4i*)(tpre + u0);      // cached: reused by k5
        v4i post = __builtin_nontemporal_load((const v4i*)(tpost + u0));
        float f[4];
        #pragma unroll
        for (int j = 0; j < 4; ++j) {
            v4f a0 = __builtin_nontemporal_load((const v4f*)(attrs + (size_t)(u0 + j) * 8));
            v4f a1 = __builtin_nontemporal_load((const v4f*)(attrs + (size_t)(u0 + j) * 8 + 4));
            float logit = a0.x*w0.x + a0.y*w0.y + a0.z*w0.z + a0.w*w0.w +
                          a1.x*w1.x + a1.y*w1.y + a1.z*w1.z + a1.w*w1.w + b;
            float sig = 1.0f / (1.0f + __expf(-logit));
            f[j] = ((const float*)&r)[j] * sig;
        }
        delta[pre.x]  =  f[0]; delta[pre.y]  =  f[1];
        delta[pre.z]  =  f[2]; delta[pre.w]  =  f[3];
        delta[post.x] = -f[0]; delta[post.y] = -f[1];
        delta[post.z] = -f[2]; delta[post.w] = -f[3];
    } else {
        for (int u = u0; u < N; ++u) {
            float logit = b;
            #pragma unroll
            for (int k = 0; k < 8; ++k) logit += attrs[(size_t)u * 8 + k] * weight[k];
            float sig = 1.0f / (1.0f + __expf(-logit));
            float f = residues[u] * sig;
            delta[tpre[u]]  =  f;
            delta[tpost[u]] = -f;
        }
    }
}

// ---------------------------------------------------------------------------
// Single-pass inclusive scan over delta (in place): decoupled lookback with
// atomic-ticket tile ordering (dispatch-order safe: a tile only waits on
// lower tickets, which have already started).
__global__ void scan_onepass(float* __restrict__ data,
                             unsigned long long* __restrict__ state,
                             int* __restrict__ ticket, int T) {
    __shared__ int s_tile;
    __shared__ float s_carry;
    __shared__ float wavesums[SCAN_THREADS / 64];
    if (threadIdx.x == 0) s_tile = atomicAdd(ticket, 1);
    __syncthreads();
    const int tile = s_tile;
    const int base = tile * CHUNK + threadIdx.x * EPT;

    float v[EPT];
    bool full = (base + EPT <= T);
    if (full) {
        v4f a = *(const v4f*)(data + base);
        v4f c = *(const v4f*)(data + base + 4);
        v[0]=a.x; v[1]=a.y; v[2]=a.z; v[3]=a.w;
        v[4]=c.x; v[5]=c.y; v[6]=c.z; v[7]=c.w;
    } else {
        for (int i = 0; i < EPT; ++i) v[i] = (base + i < T) ? data[base + i] : 0.0f;
    }
    float run = 0.0f;
    #pragma unroll
    for (int i = 0; i < EPT; ++i) { run += v[i]; v[i] = run; }
    float tot = run;

    int lane = threadIdx.x & 63, wid = threadIdx.x >> 6;
    float x = tot;
    #pragma unroll
    for (int d = 1; d < 64; d <<= 1) {
        float y = __shfl_up(x, d, 64);
        if (lane >= d) x += y;
    }
    if (lane == 63) wavesums[wid] = x;
    __syncthreads();
    float agg = 0.0f, woff = 0.0f;
    #pragma unroll
    for (int i = 0; i < SCAN_THREADS / 64; ++i) {
        if (i < wid) woff += wavesums[i];
        agg += wavesums[i];
    }
    float texcl = (x - tot) + woff;      // block-exclusive prefix of this thread

    if (threadIdx.x == 0) {
        unsigned long long p = pack_sf(agg, (tile == 0) ? 2u : 1u);
        __hip_atomic_store(&state[tile], p, __ATOMIC_RELEASE, __HIP_MEMORY_SCOPE_AGENT);
    }

    if (wid == 0) {                       // wave 0 does parallel lookback
        float carry = 0.0f;
        if (tile > 0) {
            int offset = 0;
            while (true) {
                int idx = tile - 1 - offset - lane;
                float val; int flg;
                if (idx >= 0) {
                    unsigned long long p;
                    do {
                        p = __hip_atomic_load(&state[idx], __ATOMIC_ACQUIRE,
                                              __HIP_MEMORY_SCOPE_AGENT);
                        flg = (int)(p >> 32);
                    } while (flg == 0);
                    val = __uint_as_float((unsigned)(p & 0xffffffffu));
                } else { val = 0.0f; flg = 2; }
                unsigned long long m2 = __ballot(flg == 2);
                int L = (m2 != 0) ? (__ffsll((unsigned long long)m2) - 1) : 64;
                float contrib = (lane <= L) ? val : 0.0f;
                #pragma unroll
                for (int d = 32; d > 0; d >>= 1) contrib += __shfl_down(contrib, d, 64);
                contrib = __shfl(contrib, 0, 64);
                carry += contrib;
                if (m2 != 0) break;
                offset += 64;
            }
        }
        if (lane == 0) {
            s_carry = carry;
            if (tile > 0) {
                unsigned long long p = pack_sf(carry + agg, 2u);
                __hip_atomic_store(&state[tile], p, __ATOMIC_RELEASE,
                                   __HIP_MEMORY_SCOPE_AGENT);
            }
        }
    }
    __syncthreads();
    float add = s_carry + texcl;

    if (full) {
        v4f o0 = { v[0]+add, v[1]+add, v[2]+add, v[3]+add };
        v4f o1 = { v[4]+add, v[5]+add, v[6]+add, v[7]+add };
        *(v4f*)(data + base)     = o0;
        *(v4f*)(data + base + 4) = o1;
    } else {
        for (int i = 0; i < EPT; ++i)
            if (base + i < T) data[base + i] = v[i] + add;
    }
}

// ---------------------------------------------------------------------------
// K5: vnode[u] = ycum[tpre[u]]; 8 gathers per thread.
__global__ void k5_node_values(const float* __restrict__ ycum,
                               const int* __restrict__ tpre,
                               float* __restrict__ vnode, int N) {
    int u0 = (blockIdx.x * blockDim.x + threadIdx.x) * 8;
    if (u0 + 8 <= N) {
        v4i t0 = *(const v4i*)(tpre + u0);
        v4i t1 = *(const v4i*)(tpre + u0 + 4);
        v4f o0 = { ycum[t0.x], ycum[t0.y], ycum[t0.z], ycum[t0.w] };
        v4f o1 = { ycum[t1.x], ycum[t1.y], ycum[t1.z], ycum[t1.w] };
        *(v4f*)(vnode + u0)     = o0;   // normal store: keep vnode in L2 for k6
        *(v4f*)(vnode + u0 + 4) = o1;
    } else {
        for (int u = u0; u < N; ++u) vnode[u] = ycum[tpre[u]];
    }
}

// ---------------------------------------------------------------------------
// K6: per-pixel gather, 16 pixels/thread; nt-stream nop & out so vnode
// stays L2-resident.
__global__ void k6_gather(const float* __restrict__ vnode,
                          const int* __restrict__ nop,
                          float* __restrict__ out, int P) {
    int i = (blockIdx.x * blockDim.x + threadIdx.x) * 16;
    if (i + 16 <= P) {
        v4i n0 = __builtin_nontemporal_load((const v4i*)(nop + i));
        v4i n1 = __builtin_nontemporal_load((const v4i*)(nop + i + 4));
        v4i n2 = __builtin_nontemporal_load((const v4i*)(nop + i + 8));
        v4i n3 = __builtin_nontemporal_load((const v4i*)(nop + i + 12));
        v4f o0 = { vnode[n0.x], vnode[n0.y], vnode[n0.z], vnode[n0.w] };
        v4f o1 = { vnode[n1.x], vnode[n1.y], vnode[n1.z], vnode[n1.w] };
        v4f o2 = { vnode[n2.x], vnode[n2.y], vnode[n2.z], vnode[n2.w] };
        v4f o3 = { vnode[n3.x], vnode[n3.y], vnode[n3.z], vnode[n3.w] };
        __builtin_nontemporal_store(o0, (v4f*)(out + i));
        __builtin_nontemporal_store(o1, (v4f*)(out + i + 4));
        __builtin_nontemporal_store(o2, (v4f*)(out + i + 8));
        __builtin_nontemporal_store(o3, (v4f*)(out + i + 12));
    } else {
        for (; i < P; ++i) out[i] = vnode[nop[i]];
    }
}

// K6 fallback: direct double gather (only used if ws is tiny).
__global__ void k6_direct(const float* __restrict__ ycum,
                          const int* __restrict__ tpre,
                          const int* __restrict__ nop,
                          float* __restrict__ out, int P) {
    int i = (blockIdx.x * blockDim.x + threadIdx.x) * 4;
    if (i + 4 <= P) {
        v4i n = *(const v4i*)(nop + i);
        v4f o = { ycum[tpre[n.x]], ycum[tpre[n.y]], ycum[tpre[n.z]], ycum[tpre[n.w]] };
        *(v4f*)(out + i) = o;
    } else {
        for (; i < P; ++i) out[i] = ycum[tpre[nop[i]]];
    }
}

extern "C" void kernel_launch(void* const* d_in, const int* in_sizes, int n_in,
                              void* d_out, int out_size, void* d_ws, size_t ws_size,
                              hipStream_t stream) {
    const float* weight   = (const float*)d_in[0];
    const float* bias     = (const float*)d_in[1];
    const float* residues = (const float*)d_in[2];
    const float* attrs    = (const float*)d_in[3];
    const int*   tpre     = (const int*)d_in[4];
    const int*   tpost    = (const int*)d_in[5];
    const int*   nop      = (const int*)d_in[6];
    float* out = (float*)d_out;

    const int N = in_sizes[2];        // 500,000
    const int T = 2 * N;              // 1,000,000
    const int P = out_size;           // 8,388,608
    const int numChunks = (T + CHUNK - 1) / CHUNK;   // 489

    const size_t ctrlBytes = 1024 * sizeof(unsigned long long) + 64;
    size_t needFull = (size_t)(T + N) * sizeof(float) + ctrlBytes;
    size_t needMid  = (size_t)N * sizeof(float) + ctrlBytes;

    float* delta;
    float* vnode = nullptr;
    unsigned long long* state;
    bool useVnode = true;

    if (ws_size >= needFull) {
        delta = (float*)d_ws;
        vnode = delta + T;
        state = (unsigned long long*)(vnode + N);
    } else if (ws_size >= needMid) {
        delta = out;                  // dead until k6 rewrites it fully
        vnode = (float*)d_ws;
        state = (unsigned long long*)(vnode + N);
    } else {
        delta = out;
        state = (unsigned long long*)d_ws;
        useVnode = false;
    }
    int* ticket = (int*)(state + 1024);

    // zero lookback state + ticket (ws is poisoned 0xAA before every call)
    hipMemsetAsync(state, 0, ctrlBytes, stream);

    k1_filter_scatter<<<(N / 4 + 255) / 256, 256, 0, stream>>>(
        attrs, weight, bias, residues, tpre, tpost, delta, N);
    scan_onepass<<<numChunks, SCAN_THREADS, 0, stream>>>(delta, state, ticket, T);

    if (useVnode) {
        k5_node_values<<<(N / 8 + 255) / 256, 256, 0, stream>>>(delta, tpre, vnode, N);
        int gatherBlocks = (P / 16 + 255) / 256;
        k6_gather<<<gatherBlocks, 256, 0, stream>>>(vnode, nop, out, P);
    } else {
        int gatherBlocks = (P / 4 + 255) / 256;
        k6_direct<<<gatherBlocks, 256, 0, stream>>>(delta, tpre, nop, out, P);
    }
}

// Round 4
// 182.562 us; speedup vs baseline: 1.2313x; 1.2313x over previous
//
#include <hip/hip_runtime.h>

#define SCAN_THREADS 256
#define EPT 8
#define CHUNK (SCAN_THREADS * EPT)   // 2048 elements per scan block

typedef int   v4i __attribute__((ext_vector_type(4)));
typedef float v4f __attribute__((ext_vector_type(4)));

// ---------------------------------------------------------------------------
// K1: filtered = residues * sigmoid(attrs @ w + b); scatter +/- into delta.
// tpre u tpost is a permutation of [0,2N) -> every slot written exactly once.
// 4 nodes/thread for scatter ILP; nt loads on single-use streams.
__global__ void k1_filter_scatter(const float* __restrict__ attrs,
                                  const float* __restrict__ weight,
                                  const float* __restrict__ bias,
                                  const float* __restrict__ residues,
                                  const int* __restrict__ tpre,
                                  const int* __restrict__ tpost,
                                  float* __restrict__ delta,
                                  int N) {
    int u0 = (blockIdx.x * blockDim.x + threadIdx.x) * 4;
    v4f w0 = *(const v4f*)weight;
    v4f w1 = *(const v4f*)(weight + 4);
    float b = bias[0];
    if (u0 + 4 <= N) {
        v4f r    = __builtin_nontemporal_load((const v4f*)(residues + u0));
        v4i pre  = *(const v4i*)(tpre + u0);      // reused later by k5: cache
        v4i post = __builtin_nontemporal_load((const v4i*)(tpost + u0));
        float f[4];
        #pragma unroll
        for (int j = 0; j < 4; ++j) {
            v4f a0 = __builtin_nontemporal_load((const v4f*)(attrs + (size_t)(u0 + j) * 8));
            v4f a1 = __builtin_nontemporal_load((const v4f*)(attrs + (size_t)(u0 + j) * 8 + 4));
            float logit = a0.x*w0.x + a0.y*w0.y + a0.z*w0.z + a0.w*w0.w +
                          a1.x*w1.x + a1.y*w1.y + a1.z*w1.z + a1.w*w1.w + b;
            float sig = 1.0f / (1.0f + __expf(-logit));
            f[j] = r[j] * sig;
        }
        delta[pre.x]  =  f[0]; delta[pre.y]  =  f[1];
        delta[pre.z]  =  f[2]; delta[pre.w]  =  f[3];
        delta[post.x] = -f[0]; delta[post.y] = -f[1];
        delta[post.z] = -f[2]; delta[post.w] = -f[3];
    } else {
        for (int u = u0; u < N; ++u) {
            float logit = b;
            #pragma unroll
            for (int k = 0; k < 8; ++k) logit += attrs[(size_t)u * 8 + k] * weight[k];
            float sig = 1.0f / (1.0f + __expf(-logit));
            float f = residues[u] * sig;
            delta[tpre[u]]  =  f;
            delta[tpost[u]] = -f;
        }
    }
}

// ---------------------------------------------------------------------------
// K2: per-chunk partial sums.
__global__ void k2_partials(const float* __restrict__ delta,
                            float* __restrict__ partials, int T) {
    __shared__ float sdata[SCAN_THREADS / 64];
    int base = blockIdx.x * CHUNK + threadIdx.x * EPT;
    float s = 0.0f;
    if (base + EPT <= T) {
        v4f v0 = *(const v4f*)(delta + base);
        v4f v1 = *(const v4f*)(delta + base + 4);
        s = v0.x + v0.y + v0.z + v0.w + v1.x + v1.y + v1.z + v1.w;
    } else {
        for (int i = 0; i < EPT; ++i)
            if (base + i < T) s += delta[base + i];
    }
    #pragma unroll
    for (int d = 32; d > 0; d >>= 1) s += __shfl_down(s, d, 64);
    int lane = threadIdx.x & 63, wid = threadIdx.x >> 6;
    if (lane == 0) sdata[wid] = s;
    __syncthreads();
    if (threadIdx.x == 0) {
        float tot = 0.0f;
        #pragma unroll
        for (int i = 0; i < SCAN_THREADS / 64; ++i) tot += sdata[i];
        partials[blockIdx.x] = tot;
    }
}

// ---------------------------------------------------------------------------
// K3: single-wave exclusive scan of chunk partials -> chunk offsets.
__global__ void k3_scan_partials(const float* __restrict__ partials,
                                 float* __restrict__ offsets, int numChunks) {
    int lane = threadIdx.x;          // launched with 64 threads
    int ppl = (numChunks + 63) >> 6; // partials per lane
    float s = 0.0f;
    for (int i = 0; i < ppl; ++i) {
        int idx = lane * ppl + i;
        if (idx < numChunks) s += partials[idx];
    }
    float x = s;
    #pragma unroll
    for (int d = 1; d < 64; d <<= 1) {
        float y = __shfl_up(x, d, 64);
        if (lane >= d) x += y;
    }
    float run = x - s; // exclusive prefix of this lane's segment
    for (int i = 0; i < ppl; ++i) {
        int idx = lane * ppl + i;
        if (idx < numChunks) { offsets[idx] = run; run += partials[idx]; }
    }
}

// ---------------------------------------------------------------------------
// K4: in-place inclusive scan of each chunk + chunk offset.
__global__ void k4_scan_chunks(float* __restrict__ data,
                               const float* __restrict__ offsets, int T) {
    __shared__ float wavesums[SCAN_THREADS / 64];
    int base = blockIdx.x * CHUNK + threadIdx.x * EPT;
    float v[EPT];
    bool full = (base + EPT <= T);
    if (full) {
        v4f v0 = *(const v4f*)(data + base);
        v4f v1 = *(const v4f*)(data + base + 4);
        v[0]=v0.x; v[1]=v0.y; v[2]=v0.z; v[3]=v0.w;
        v[4]=v1.x; v[5]=v1.y; v[6]=v1.z; v[7]=v1.w;
    } else {
        for (int i = 0; i < EPT; ++i)
            v[i] = (base + i < T) ? data[base + i] : 0.0f;
    }
    float run = 0.0f;
    #pragma unroll
    for (int i = 0; i < EPT; ++i) { run += v[i]; v[i] = run; }
    float tot = run;
    int lane = threadIdx.x & 63, wid = threadIdx.x >> 6;
    float x = tot;
    #pragma unroll
    for (int d = 1; d < 64; d <<= 1) {
        float y = __shfl_up(x, d, 64);
        if (lane >= d) x += y;
    }
    if (lane == 63) wavesums[wid] = x;
    __syncthreads();
    float woff = 0.0f;
    #pragma unroll
    for (int i = 0; i < SCAN_THREADS / 64; ++i)
        if (i < wid) woff += wavesums[i];
    float add = (x - tot) + woff + offsets[blockIdx.x];
    if (full) {
        v4f o0 = { v[0]+add, v[1]+add, v[2]+add, v[3]+add };
        v4f o1 = { v[4]+add, v[5]+add, v[6]+add, v[7]+add };
        *(v4f*)(data + base)     = o0;
        *(v4f*)(data + base + 4) = o1;
    } else {
        for (int i = 0; i < EPT; ++i)
            if (base + i < T) data[base + i] = v[i] + add;
    }
}

// ---------------------------------------------------------------------------
// K5: vnode[u] = ycum[tpre[u]]; 8 gathers/thread.
__global__ void k5_node_values(const float* __restrict__ ycum,
                               const int* __restrict__ tpre,
                               float* __restrict__ vnode, int N) {
    int u0 = (blockIdx.x * blockDim.x + threadIdx.x) * 8;
    if (u0 + 8 <= N) {
        v4i t0 = *(const v4i*)(tpre + u0);
        v4i t1 = *(const v4i*)(tpre + u0 + 4);
        v4f o0 = { ycum[t0.x], ycum[t0.y], ycum[t0.z], ycum[t0.w] };
        v4f o1 = { ycum[t1.x], ycum[t1.y], ycum[t1.z], ycum[t1.w] };
        *(v4f*)(vnode + u0)     = o0;
        *(v4f*)(vnode + u0 + 4) = o1;
    } else {
        for (int u = u0; u < N; ++u) vnode[u] = ycum[tpre[u]];
    }
}

// ---------------------------------------------------------------------------
// K6: per-pixel gather, 16 px/thread for MLP; nt loads on nop (single use),
// NORMAL stores on out (nt stores tripled WRITE_SIZE in round 2).
__global__ void k6_gather(const float* __restrict__ vnode,
                          const int* __restrict__ nop,
                          float* __restrict__ out, int P) {
    int i = (blockIdx.x * blockDim.x + threadIdx.x) * 16;
    if (i + 16 <= P) {
        v4i n0 = __builtin_nontemporal_load((const v4i*)(nop + i));
        v4i n1 = __builtin_nontemporal_load((const v4i*)(nop + i + 4));
        v4i n2 = __builtin_nontemporal_load((const v4i*)(nop + i + 8));
        v4i n3 = __builtin_nontemporal_load((const v4i*)(nop + i + 12));
        v4f o0 = { vnode[n0.x], vnode[n0.y], vnode[n0.z], vnode[n0.w] };
        v4f o1 = { vnode[n1.x], vnode[n1.y], vnode[n1.z], vnode[n1.w] };
        v4f o2 = { vnode[n2.x], vnode[n2.y], vnode[n2.z], vnode[n2.w] };
        v4f o3 = { vnode[n3.x], vnode[n3.y], vnode[n3.z], vnode[n3.w] };
        *(v4f*)(out + i)      = o0;
        *(v4f*)(out + i + 4)  = o1;
        *(v4f*)(out + i + 8)  = o2;
        *(v4f*)(out + i + 12) = o3;
    } else {
        for (; i < P; ++i) out[i] = vnode[nop[i]];
    }
}

// K6 fallback: direct double gather (tiny-ws tier only).
__global__ void k6_direct(const float* __restrict__ ycum,
                          const int* __restrict__ tpre,
                          const int* __restrict__ nop,
                          float* __restrict__ out, int P) {
    int i = (blockIdx.x * blockDim.x + threadIdx.x) * 4;
    if (i + 4 <= P) {
        v4i n = *(const v4i*)(nop + i);
        v4f o = { ycum[tpre[n.x]], ycum[tpre[n.y]], ycum[tpre[n.z]], ycum[tpre[n.w]] };
        *(v4f*)(out + i) = o;
    } else {
        for (; i < P; ++i) out[i] = ycum[tpre[nop[i]]];
    }
}

extern "C" void kernel_launch(void* const* d_in, const int* in_sizes, int n_in,
                              void* d_out, int out_size, void* d_ws, size_t ws_size,
                              hipStream_t stream) {
    const float* weight   = (const float*)d_in[0];
    const float* bias     = (const float*)d_in[1];
    const float* residues = (const float*)d_in[2];
    const float* attrs    = (const float*)d_in[3];
    const int*   tpre     = (const int*)d_in[4];
    const int*   tpost    = (const int*)d_in[5];
    const int*   nop      = (const int*)d_in[6];
    float* out = (float*)d_out;

    const int N = in_sizes[2];        // 500,000
    const int T = 2 * N;              // 1,000,000
    const int P = out_size;           // 8,388,608
    const int numChunks = (T + CHUNK - 1) / CHUNK;   // 489

    size_t needFull = (size_t)(T + N + 2 * 1024) * sizeof(float);
    size_t needMid  = (size_t)(N + 2 * 1024) * sizeof(float);

    float* delta;
    float* vnode    = nullptr;
    float* partials;
    float* offsets;
    bool useVnode = true;

    if (ws_size >= needFull) {
        delta    = (float*)d_ws;
        vnode    = delta + T;
        partials = vnode + N;
        offsets  = partials + 1024;
    } else if (ws_size >= needMid) {
        delta    = out;               // dead until k6 rewrites it fully
        vnode    = (float*)d_ws;
        partials = vnode + N;
        offsets  = partials + 1024;
    } else {
        delta    = out;
        partials = (float*)d_ws;
        offsets  = partials + 1024;
        useVnode = false;
    }

    k1_filter_scatter<<<(N / 4 + 255) / 256, 256, 0, stream>>>(
        attrs, weight, bias, residues, tpre, tpost, delta, N);
    k2_partials<<<numChunks, SCAN_THREADS, 0, stream>>>(delta, partials, T);
    k3_scan_partials<<<1, 64, 0, stream>>>(partials, offsets, numChunks);
    k4_scan_chunks<<<numChunks, SCAN_THREADS, 0, stream>>>(delta, offsets, T);

    if (useVnode) {
        k5_node_values<<<(N / 8 + 255) / 256, 256, 0, stream>>>(delta, tpre, vnode, N);
        int gatherBlocks = (P / 16 + 255) / 256;
        k6_gather<<<gatherBlocks, 256, 0, stream>>>(vnode, nop, out, P);
    } else {
        int gatherBlocks = (P / 4 + 255) / 256;
        k6_direct<<<gatherBlocks, 256, 0, stream>>>(delta, tpre, nop, out, P);
    }
}

// Round 5
// 163.787 us; speedup vs baseline: 1.3725x; 1.1146x over previous
//
#include <hip/hip_runtime.h>

#define SCAN_THREADS 256
#define EPT 8
#define CHUNK (SCAN_THREADS * EPT)   // 2048 elements per scan block

typedef int   v4i __attribute__((ext_vector_type(4)));
typedef float v4f __attribute__((ext_vector_type(4)));

// ---------------------------------------------------------------------------
// K1: filtered = residues * sigmoid(attrs @ w + b); scatter +/- into delta.
// tpre u tpost is a permutation of [0,2N) -> every slot written exactly once.
// 2 nodes/thread -> 977 blocks (parallelism for scatter latency hiding).
__global__ void k1_filter_scatter(const float* __restrict__ attrs,
                                  const float* __restrict__ weight,
                                  const float* __restrict__ bias,
                                  const float* __restrict__ residues,
                                  const int* __restrict__ tpre,
                                  const int* __restrict__ tpost,
                                  float* __restrict__ delta,
                                  int N) {
    int u0 = (blockIdx.x * blockDim.x + threadIdx.x) * 2;
    v4f w0 = *(const v4f*)weight;
    v4f w1 = *(const v4f*)(weight + 4);
    float b = bias[0];
    if (u0 + 2 <= N) {
        float r0 = residues[u0], r1 = residues[u0 + 1];
        int pre0 = tpre[u0],  pre1 = tpre[u0 + 1];
        int pos0 = tpost[u0], pos1 = tpost[u0 + 1];
        v4f a00 = *(const v4f*)(attrs + (size_t)u0 * 8);
        v4f a01 = *(const v4f*)(attrs + (size_t)u0 * 8 + 4);
        v4f a10 = *(const v4f*)(attrs + (size_t)u0 * 8 + 8);
        v4f a11 = *(const v4f*)(attrs + (size_t)u0 * 8 + 12);
        float l0 = a00.x*w0.x + a00.y*w0.y + a00.z*w0.z + a00.w*w0.w +
                   a01.x*w1.x + a01.y*w1.y + a01.z*w1.z + a01.w*w1.w + b;
        float l1 = a10.x*w0.x + a10.y*w0.y + a10.z*w0.z + a10.w*w0.w +
                   a11.x*w1.x + a11.y*w1.y + a11.z*w1.z + a11.w*w1.w + b;
        float f0 = r0 / (1.0f + __expf(-l0));
        float f1 = r1 / (1.0f + __expf(-l1));
        delta[pre0] =  f0; delta[pre1] =  f1;
        delta[pos0] = -f0; delta[pos1] = -f1;
    } else {
        for (int u = u0; u < N; ++u) {
            float logit = b;
            #pragma unroll
            for (int k = 0; k < 8; ++k) logit += attrs[(size_t)u * 8 + k] * weight[k];
            float f = residues[u] / (1.0f + __expf(-logit));
            delta[tpre[u]]  =  f;
            delta[tpost[u]] = -f;
        }
    }
}

// ---------------------------------------------------------------------------
// K2: per-chunk partial sums.
__global__ void k2_partials(const float* __restrict__ delta,
                            float* __restrict__ partials, int T) {
    __shared__ float sdata[SCAN_THREADS / 64];
    int base = blockIdx.x * CHUNK + threadIdx.x * EPT;
    float s = 0.0f;
    if (base + EPT <= T) {
        v4f v0 = *(const v4f*)(delta + base);
        v4f v1 = *(const v4f*)(delta + base + 4);
        s = v0.x + v0.y + v0.z + v0.w + v1.x + v1.y + v1.z + v1.w;
    } else {
        for (int i = 0; i < EPT; ++i)
            if (base + i < T) s += delta[base + i];
    }
    #pragma unroll
    for (int d = 32; d > 0; d >>= 1) s += __shfl_down(s, d, 64);
    int lane = threadIdx.x & 63, wid = threadIdx.x >> 6;
    if (lane == 0) sdata[wid] = s;
    __syncthreads();
    if (threadIdx.x == 0)
        partials[blockIdx.x] = sdata[0] + sdata[1] + sdata[2] + sdata[3];
}

// ---------------------------------------------------------------------------
// K4: in-place inclusive scan of each chunk; each block derives its own
// offset by reducing partials[0..blockIdx.x) (<=489 L2-hot floats) — k3 gone.
__global__ void k4_scan_chunks(float* __restrict__ data,
                               const float* __restrict__ partials, int T) {
    __shared__ float wavesums[SCAN_THREADS / 64];
    __shared__ float redsum[SCAN_THREADS / 64];
    int lane = threadIdx.x & 63, wid = threadIdx.x >> 6;

    // Chunk offset = sum of partials of preceding chunks.
    float c = 0.0f;
    for (int i = threadIdx.x; i < blockIdx.x; i += SCAN_THREADS)
        c += partials[i];
    #pragma unroll
    for (int d = 32; d > 0; d >>= 1) c += __shfl_down(c, d, 64);
    if (lane == 0) redsum[wid] = c;

    int base = blockIdx.x * CHUNK + threadIdx.x * EPT;
    float v[EPT];
    bool full = (base + EPT <= T);
    if (full) {
        v4f v0 = *(const v4f*)(data + base);
        v4f v1 = *(const v4f*)(data + base + 4);
        v[0]=v0.x; v[1]=v0.y; v[2]=v0.z; v[3]=v0.w;
        v[4]=v1.x; v[5]=v1.y; v[6]=v1.z; v[7]=v1.w;
    } else {
        for (int i = 0; i < EPT; ++i)
            v[i] = (base + i < T) ? data[base + i] : 0.0f;
    }
    float run = 0.0f;
    #pragma unroll
    for (int i = 0; i < EPT; ++i) { run += v[i]; v[i] = run; }
    float tot = run;
    float x = tot;
    #pragma unroll
    for (int d = 1; d < 64; d <<= 1) {
        float y = __shfl_up(x, d, 64);
        if (lane >= d) x += y;
    }
    if (lane == 63) wavesums[wid] = x;
    __syncthreads();
    float woff = 0.0f, offset = redsum[0] + redsum[1] + redsum[2] + redsum[3];
    #pragma unroll
    for (int i = 0; i < SCAN_THREADS / 64; ++i)
        if (i < wid) woff += wavesums[i];
    float add = (x - tot) + woff + offset;
    if (full) {
        v4f o0 = { v[0]+add, v[1]+add, v[2]+add, v[3]+add };
        v4f o1 = { v[4]+add, v[5]+add, v[6]+add, v[7]+add };
        *(v4f*)(data + base)     = o0;
        *(v4f*)(data + base + 4) = o1;
    } else {
        for (int i = 0; i < EPT; ++i)
            if (base + i < T) data[base + i] = v[i] + add;
    }
}

// ---------------------------------------------------------------------------
// K5: vnode[u] = ycum[tpre[u]]; 2 nodes/thread -> 977 blocks.
__global__ void k5_node_values(const float* __restrict__ ycum,
                               const int* __restrict__ tpre,
                               float* __restrict__ vnode, int N) {
    int u0 = (blockIdx.x * blockDim.x + threadIdx.x) * 2;
    if (u0 + 2 <= N) {
        int t0 = tpre[u0], t1 = tpre[u0 + 1];
        float y0 = ycum[t0], y1 = ycum[t1];
        vnode[u0] = y0; vnode[u0 + 1] = y1;
    } else {
        for (int u = u0; u < N; ++u) vnode[u] = ycum[tpre[u]];
    }
}

// ---------------------------------------------------------------------------
// K6: per-pixel gather, 8 px/thread, 4096 blocks, plain cached loads.
__global__ void k6_gather(const float* __restrict__ vnode,
                          const int* __restrict__ nop,
                          float* __restrict__ out, int P) {
    int i = (blockIdx.x * blockDim.x + threadIdx.x) * 8;
    if (i + 8 <= P) {
        v4i n0 = *(const v4i*)(nop + i);
        v4i n1 = *(const v4i*)(nop + i + 4);
        v4f o0 = { vnode[n0.x], vnode[n0.y], vnode[n0.z], vnode[n0.w] };
        v4f o1 = { vnode[n1.x], vnode[n1.y], vnode[n1.z], vnode[n1.w] };
        *(v4f*)(out + i)     = o0;
        *(v4f*)(out + i + 4) = o1;
    } else {
        for (; i < P; ++i) out[i] = vnode[nop[i]];
    }
}

// K6 fallback: direct double gather (tiny-ws tier only).
__global__ void k6_direct(const float* __restrict__ ycum,
                          const int* __restrict__ tpre,
                          const int* __restrict__ nop,
                          float* __restrict__ out, int P) {
    int i = (blockIdx.x * blockDim.x + threadIdx.x) * 4;
    if (i + 4 <= P) {
        v4i n = *(const v4i*)(nop + i);
        v4f o = { ycum[tpre[n.x]], ycum[tpre[n.y]], ycum[tpre[n.z]], ycum[tpre[n.w]] };
        *(v4f*)(out + i) = o;
    } else {
        for (; i < P; ++i) out[i] = ycum[tpre[nop[i]]];
    }
}

extern "C" void kernel_launch(void* const* d_in, const int* in_sizes, int n_in,
                              void* d_out, int out_size, void* d_ws, size_t ws_size,
                              hipStream_t stream) {
    const float* weight   = (const float*)d_in[0];
    const float* bias     = (const float*)d_in[1];
    const float* residues = (const float*)d_in[2];
    const float* attrs    = (const float*)d_in[3];
    const int*   tpre     = (const int*)d_in[4];
    const int*   tpost    = (const int*)d_in[5];
    const int*   nop      = (const int*)d_in[6];
    float* out = (float*)d_out;

    const int N = in_sizes[2];        // 500,000
    const int T = 2 * N;              // 1,000,000
    const int P = out_size;           // 8,388,608
    const int numChunks = (T + CHUNK - 1) / CHUNK;   // 489

    size_t needFull = (size_t)(T + N + 1024) * sizeof(float);
    size_t needMid  = (size_t)(N + 1024) * sizeof(float);

    float* delta;
    float* vnode    = nullptr;
    float* partials;
    bool useVnode = true;

    if (ws_size >= needFull) {
        delta    = (float*)d_ws;
        vnode    = delta + T;
        partials = vnode + N;
    } else if (ws_size >= needMid) {
        delta    = out;               // dead until k6 rewrites it fully
        vnode    = (float*)d_ws;
        partials = vnode + N;
    } else {
        delta    = out;
        partials = (float*)d_ws;
        useVnode = false;
    }

    k1_filter_scatter<<<(N / 2 + 255) / 256, 256, 0, stream>>>(
        attrs, weight, bias, residues, tpre, tpost, delta, N);
    k2_partials<<<numChunks, SCAN_THREADS, 0, stream>>>(delta, partials, T);
    k4_scan_chunks<<<numChunks, SCAN_THREADS, 0, stream>>>(delta, partials, T);

    if (useVnode) {
        k5_node_values<<<(N / 2 + 255) / 256, 256, 0, stream>>>(delta, tpre, vnode, N);
        int gatherBlocks = (P / 8 + 255) / 256;
        k6_gather<<<gatherBlocks, 256, 0, stream>>>(vnode, nop, out, P);
    } else {
        int gatherBlocks = (P / 4 + 255) / 256;
        k6_direct<<<gatherBlocks, 256, 0, stream>>>(delta, tpre, nop, out, P);
    }
}